// Round 5
// baseline (237.456 us; speedup 1.0000x reference)
//
#include <hip/hip_runtime.h>
#include <stdint.h>

// Viterbi decoder forward: B=32, T=256, L=48, START=46, END=47.
// R5: barrier-free single-wave recurrences.
//  role 0 (32 WGs): wave0 runs value-only Viterbi (48 readlane+add per step,
//    6-row global_load_lds ring, constant vmcnt(36), 1 hist write/step);
//    then all 4 waves recompute backpointers in parallel (bit-identical),
//    then chunked traceback.
//  role 1 (32 WGs): logsumexp in probability domain: P = E^T P per step
//    (48 fmac, no transcendentals on the chain; ldexp renorm); 3 helper
//    waves stage exp'd rows into a 4-slot ring, barrier every 2 steps.

#define TT 256
#define LL 48
#define ROWF 2304          // 48*48 floats per time-row
#define LSTART 46
#define LEND 47
#define BB 32
#define LOG2E 1.44269504088896f
#define LN2 0.693147180559945f

#define GLL(GP, LP) __builtin_amdgcn_global_load_lds( \
    (const __attribute__((address_space(1))) void*)(GP), \
    (__attribute__((address_space(3))) void*)(LP), 16, 0, 0)

#define RL(var, lane) __int_as_float(__builtin_amdgcn_readlane(__float_as_int(var), (lane)))

__launch_bounds__(256, 1)
__global__ void viterbi_fwd(const float* __restrict__ em,
                            const float* __restrict__ tr,
                            const int* __restrict__ len_raw,
                            float* __restrict__ out,
                            float* __restrict__ ws)
{
  const int role = blockIdx.x >> 5;   // 0 = Viterbi, 1 = LSE
  const int b    = blockIdx.x & 31;
  const int tid  = threadIdx.x;
  const int w    = tid >> 6;
  const int j    = tid & 63;
  const bool act = (j < LL);
  const int jl   = act ? j : (LL - 1);

  // lengths int32-or-int64 detection (values 128..256)
  int len;
  {
    bool is64 = (len_raw[1] == 0) && (len_raw[3] == 0) && (len_raw[5] == 0);
    len = is64 ? len_raw[2*b] : len_raw[b];
    if (len > TT) len = TT;
    if (len < 1) len = 1;
  }

  __shared__ float ring[6*ROWF];            // V: raw rows; LSE: 4x3072 E-ring
  __shared__ float bestHist[TT*LL];         // V only
  __shared__ float trL[ROWF];               // V bp-phase transition copy
  __shared__ unsigned char bp[TT*LL];
  __shared__ unsigned char cmp_[16*LL];
  __shared__ unsigned char entry_[16];
  __shared__ unsigned char raw[TT];

  const float* emB = em + (size_t)b*TT*ROWF;

  if (role == 0) {
    // ================= Viterbi =================
    if (w == 0) {
      float trg[LL];
      #pragma unroll
      for (int i = 0; i < LL; ++i) trg[i] = tr[i*LL + jl];
      const float init = emB[LSTART*LL + jl] + tr[LSTART*LL + jl];
      float vbest = act ? init : -INFINITY;
      if (act) bestHist[j] = init;          // row 0 = best0

      // prologue: DMA rows 1..5 into slots 1..5 (9 x 16B-lds per row)
      #pragma unroll
      for (int r = 1; r <= 5; ++r) {
        const float* gs = emB + (size_t)r*ROWF + 4*j;
        float* ls = ring + r*ROWF;
        #pragma unroll
        for (int ii = 0; ii < 9; ++ii) GLL(gs + ii*256, ls + ii*256);
      }

      int sr = 1, sw = 0;   // read slot = t%6, write slot = (t+5)%6
      #pragma unroll 1
      for (int t = 1; t < len; ++t) {
        // rows t..t+4 allowed in flight (+ row just issued) -> wait 4*9
        asm volatile("s_waitcnt vmcnt(36)" ::: "memory");
        {
          int row = t + 5; if (row > TT-1) row = TT-1;   // clamp keeps count
          const float* gs = emB + (size_t)row*ROWF + 4*j;
          float* ls = ring + sw*ROWF;
          #pragma unroll
          for (int ii = 0; ii < 9; ++ii) GLL(gs + ii*256, ls + ii*256);
        }
        const float* rp = ring + sr*ROWF + jl;
        float c[LL];
        #pragma unroll
        for (int i = 0; i < LL; ++i) {
          float etr = rp[i*LL] + trg[i];     // (em+tr) -- reference order
          c[i] = etr + RL(vbest, i);         // + best
        }
        // value max tree (value only; argmax deferred to bp phase)
        #pragma unroll
        for (int i = 0; i < 24; ++i) c[i] = fmaxf(c[i], c[i+24]);
        #pragma unroll
        for (int i = 0; i < 12; ++i) c[i] = fmaxf(c[i], c[i+12]);
        #pragma unroll
        for (int i = 0; i < 6;  ++i) c[i] = fmaxf(c[i], c[i+6]);
        #pragma unroll
        for (int i = 0; i < 3;  ++i) c[i] = fmaxf(c[i], c[i+3]);
        float bv = fmaxf(fmaxf(c[0], c[1]), c[2]);
        if (act) { vbest = bv; bestHist[t*LL + j] = bv; }
        ++sr; if (sr == 6) sr = 0;
        ++sw; if (sw == 6) sw = 0;
      }
      if (j == LEND) ws[BB + b] = vbest;     // best[END]
    } else {
      // waves 1-3: prefill bp boundary rows + stage transition for bp phase
      const int t3 = tid - 64;               // 0..191
      for (int idx = t3; idx < LL; idx += 192) bp[idx] = (unsigned char)LSTART;
      for (int idx = len*LL + t3; idx < TT*LL; idx += 192) bp[idx] = (unsigned char)LEND;
      for (int idx = t3; idx < ROWF; idx += 192) trL[idx] = tr[idx];
    }
    __syncthreads();

    // ---- parallel backpointer recompute (bit-identical to fwd math) ----
    if (tid < 240) {
      const int tloc = tid / 48, l = tid - tloc*48;
      #pragma unroll 1
      for (int r = 0; r < 51; ++r) {
        const int t = r*5 + tloc + 1;
        if (t < len) {
          const float* srow = emB + (size_t)t*ROWF + l;
          float bv = -INFINITY; int ba = 0;
          #pragma unroll
          for (int i = 0; i < LL; ++i) {
            float cc = (srow[i*LL] + trL[i*LL + l]) + bestHist[(t-1)*LL + i];
            if (cc > bv) { bv = cc; ba = i; }   // strict > = first occurrence
          }
          bp[t*LL + l] = (unsigned char)ba;
        }
      }
    }
    __syncthreads();

    // ---- traceback, chunked (16 chunks x 16 steps) ----
    for (int idx = tid; idx < 16*LL; idx += 256) {
      int c = idx / LL, l = idx - c*LL;
      int pc = l;
      #pragma unroll
      for (int k = 15; k >= 0; --k) pc = bp[(16*c + k)*LL + pc];
      cmp_[c*LL + l] = (unsigned char)pc;
    }
    __syncthreads();
    if (tid == 0) {
      int pc = LEND;
      for (int c = 15; c >= 0; --c) { entry_[c] = (unsigned char)pc; pc = cmp_[c*LL + pc]; }
    }
    __syncthreads();
    if (tid < 16) {
      int c = tid, pc = entry_[c];
      #pragma unroll
      for (int k = 15; k >= 0; --k) { int t2 = 16*c + k; pc = bp[t2*LL + pc]; raw[t2] = (unsigned char)pc; }
    }
    __syncthreads();
    out[(size_t)b*TT + tid] = (tid < TT - 1) ? (float)raw[tid + 1] : (float)LEND;

  } else {
    // ================= logsumexp, probability domain =================
    // P_t = E_t^T P_{t-1},  E = exp2((em+tr)*log2e); renorm by 2^-e each
    // step (e = exponent of P[0]); upto[j] = ln2*(macc + log2 P[j]).
    float P = 0.f, macc = 0.f;
    float trgH[12];
    int   addrH[12];
    const int h = w - 1;

    if (w == 0) {
      const float init = emB[LSTART*LL + jl] + tr[LSTART*LL + jl];
      const float m2 = RL(init, 0) * LOG2E;
      P = act ? exp2f(init*LOG2E - m2) : 0.f;
      macc = m2;
    } else {
      #pragma unroll
      for (int k = 0; k < 12; ++k) {
        int m = h*768 + k*64 + j;
        trgH[k]  = tr[m];
        addrH[k] = (m / 48)*64 + (m % 48);
      }
      // prologue: rows 1,2 -> slots 1,2
      #pragma unroll
      for (int rr = 1; rr <= 2; ++rr) {
        const float* src = emB + (size_t)rr*ROWF;
        float v[12];
        #pragma unroll
        for (int k = 0; k < 12; ++k) v[k] = src[h*768 + k*64 + j];
        #pragma unroll
        for (int k = 0; k < 12; ++k)
          ring[rr*3072 + addrH[k]] = exp2f((v[k] + trgH[k]) * LOG2E);
      }
    }

    #pragma unroll 1
    for (int kw = 0; kw < 128; ++kw) {
      __syncthreads();                        // rows 2kw+1, 2kw+2 ready
      if (w == 0) {
        #pragma unroll
        for (int s = 0; s < 2; ++s) {
          const int t = 2*kw + 1 + s;
          if (t < len) {                      // uniform
            const float* cp = ring + (size_t)(t & 3)*3072 + jl;
            float a0 = 0.f, a1 = 0.f, a2 = 0.f, a3 = 0.f;
            #pragma unroll
            for (int i = 0; i < 48; i += 4) {
              a0 += cp[(i+0)*64] * RL(P, i+0);
              a1 += cp[(i+1)*64] * RL(P, i+1);
              a2 += cp[(i+2)*64] * RL(P, i+2);
              a3 += cp[(i+3)*64] * RL(P, i+3);
            }
            float Pn = (a0 + a1) + (a2 + a3);
            int rb = __builtin_amdgcn_readlane(__float_as_int(Pn), 0);
            int e  = ((rb >> 23) & 255) - 127;
            P = ldexpf(Pn, -e);
            macc += (float)e;
          }
        }
      } else {
        // stage rows 2kw+3, 2kw+4 into slots (2kw+3)&3, (2kw+0)&3 -- both
        // disjoint from the slots main reads this window.
        #pragma unroll
        for (int s = 0; s < 2; ++s) {
          int rsch = 2*kw + 3 + s;
          int slot = rsch & 3;
          int row  = rsch > TT-1 ? TT-1 : rsch;
          const float* src = emB + (size_t)row*ROWF;
          float v[12];
          #pragma unroll
          for (int k = 0; k < 12; ++k) v[k] = src[h*768 + k*64 + j];
          #pragma unroll
          for (int k = 0; k < 12; ++k)
            ring[slot*3072 + addrH[k]] = exp2f((v[k] + trgH[k]) * LOG2E);
        }
      }
    }
    if (w == 0 && j == LEND)
      ws[b] = (macc + __log2f(P)) * LN2;      // upto[END] in nats
  }
}

__global__ void viterbi_score(const float* __restrict__ ws, float* __restrict__ out)
{
  int b = threadIdx.x;
  if (b < BB) out[(size_t)BB*TT + b] = ws[BB + b] - ws[b];  // best - upto
}

extern "C" void kernel_launch(void* const* d_in, const int* in_sizes, int n_in,
                              void* d_out, int out_size, void* d_ws, size_t ws_size,
                              hipStream_t stream) {
  const float* em  = (const float*)d_in[0];
  const float* tr  = (const float*)d_in[1];
  const int*   ln  = (const int*)d_in[2];
  float* out = (float*)d_out;
  float* ws  = (float*)d_ws;
  viterbi_fwd<<<dim3(64), dim3(256), 0, stream>>>(em, tr, ln, out, ws);
  viterbi_score<<<dim3(1), dim3(64), 0, stream>>>(ws, out);
}